// Round 4
// baseline (289.755 us; speedup 1.0000x reference)
//
#include <hip/hip_runtime.h>

// ---------------------------------------------------------------------------
// MultiHeadAttention: x(4,2048,512) fp32, adj(4,2048,2048) 0/1 fp32
// R15: attn goes LDS-free. K/V per head = 512 KB (L2-resident, shared by 16
// q-blocks) and every fragment read is perfectly coalesced from global
// (K-frag: 16 rows x 64B = 1KB/instr; V pre-transposed in Vb likewise; M
// per-wave 8B/lane). So staging through LDS bought only barriers: the
// vmcnt(0)->ds_write->s_barrier chain was the exposed stall (R14 showed more
// occupancy doesn't fix it). R15: no __shared__, no __syncthreads, fragments
// loaded straight from global via per-lane pointers + immediate offsets,
// single-pass (KV-split + merge_k reverted). Math identical to R12.
// ---------------------------------------------------------------------------

typedef __attribute__((ext_vector_type(8))) short bf16x8;
typedef __attribute__((ext_vector_type(4))) float f32x4;
typedef __attribute__((ext_vector_type(4))) unsigned short ushort4v;
typedef __attribute__((ext_vector_type(4))) _Float16 f16x4;
typedef __attribute__((ext_vector_type(8))) _Float16 f16x8;
typedef __attribute__((ext_vector_type(2))) __fp16 h16x2;  // cvt_pkrtz return type

#if __has_builtin(__builtin_amdgcn_exp2f)
#define EXP2F(x) __builtin_amdgcn_exp2f(x)
#else
#define EXP2F(x) exp2f(x)
#endif

// 0.125 (1/sqrt(64)) * log2(e), folded into Q at the QKV-gemm epilogue
#define QSCALE 0.18033688011112042f

__device__ __forceinline__ unsigned short f2bf(float f) {
  unsigned int u = __float_as_uint(f);
  u += 0x7FFFu + ((u >> 16) & 1u);
  return (unsigned short)(u >> 16);
}
__device__ __forceinline__ unsigned short f2h(float f) {
  union { _Float16 h; unsigned short u; } cv;
  cv.h = (_Float16)f;
  return cv.u;
}

// sign-extend bit (pos) of w to 0 / 0xFFFFFFFF
__device__ __forceinline__ int sbit(unsigned w, int pos) {
  return ((int)(w << (31 - pos))) >> 31;  // compiler emits v_bfe_i32
}

// pack 8 floats -> f16x8 via 4 packed RTZ converts
__device__ __forceinline__ f16x8 pk8(const float* p) {
  union { struct { h16x2 a, b, c, d; } s; f16x8 v; } u;
  u.s.a = __builtin_amdgcn_cvt_pkrtz(p[0], p[1]);
  u.s.b = __builtin_amdgcn_cvt_pkrtz(p[2], p[3]);
  u.s.c = __builtin_amdgcn_cvt_pkrtz(p[4], p[5]);
  u.s.d = __builtin_amdgcn_cvt_pkrtz(p[6], p[7]);
  return u.v;
}

// PV matmul: K=32 f16 (slot pairing identical in A and B, so a two-K=16
// fallback is mathematically identical if the builtin is absent)
__device__ __forceinline__ f32x4 mfma_pv(f16x8 a, f16x8 b, f32x4 c) {
#if __has_builtin(__builtin_amdgcn_mfma_f32_16x16x32_f16)
  return __builtin_amdgcn_mfma_f32_16x16x32_f16(a, b, c, 0, 0, 0);
#else
  union { f16x8 v; struct { f16x4 lo, hi; } s; } ua, ub;
  ua.v = a; ub.v = b;
  c = __builtin_amdgcn_mfma_f32_16x16x16f16(ua.s.lo, ub.s.lo, c, 0, 0, 0);
  return __builtin_amdgcn_mfma_f32_16x16x16f16(ua.s.hi, ub.s.hi, c, 0, 0, 0);
#endif
}

// ---------------- fused prep: casts + adj bit-pack, one launch ---------------
__global__ __launch_bounds__(256) void prep_k(const float* __restrict__ x,
                                              unsigned short* __restrict__ x_bf,
                                              const float* __restrict__ wqkv,
                                              unsigned short* __restrict__ wqkv_bf,
                                              const float* __restrict__ outw,
                                              unsigned short* __restrict__ outw_bf,
                                              const float* __restrict__ adj,
                                              unsigned long long* __restrict__ abits) {
  const int bid = blockIdx.x;
  if (bid < 5120) {
    const float* in; unsigned short* out; int i;
    if (bid < 4096) { in = x; out = x_bf; i = bid * 256 + threadIdx.x; }
    else if (bid < 4864) { in = wqkv; out = wqkv_bf; i = (bid - 4096) * 256 + threadIdx.x; }
    else { in = outw; out = outw_bf; i = (bid - 4864) * 256 + threadIdx.x; }
    float4 v = ((const float4*)in)[i];
    ushort4v o;
    o[0] = f2bf(v.x); o[1] = f2bf(v.y); o[2] = f2bf(v.z); o[3] = f2bf(v.w);
    ((ushort4v*)out)[i] = o;
  } else {
    const int gw = (bid - 5120) * 4 + (threadIdx.x >> 6);  // 0..8191 = b*2048+q
    const int l = threadIdx.x & 63;
    const int b = gw >> 11, q = gw & 2047;
    const float* row = adj + ((size_t)b * 2048 + q) * 2048;
    unsigned long long* ob = abits + (size_t)b * 65536 + q;
#pragma unroll 4
    for (int kt = 0; kt < 32; ++kt) {
      const float v = row[kt * 64 + l];
      const unsigned long long m = __ballot(v != 0.f);
      if (l == 0) ob[(size_t)kt * 2048] = m;
    }
  }
}

// ---------------- 128x128 bf16 MFMA GEMM: C = A @ Bt^T (+bias) ----------------
// XCD-local tiling: blk&7 = XCD; each XCD owns a contiguous mt range so its
// L2 reuses A rows across all nt. Double-buffered LDS, one barrier/iter.
// MODE 0: QKV epilogue (Q scaled bf16 / K bf16 / V f16 LDS-transposed).
// MODE 1: fp32 + bias epilogue to f_out
template <int MODE>
__global__ __launch_bounds__(256, 3) void gemm128_k(const unsigned short* __restrict__ A,
                                                    const unsigned short* __restrict__ Bt,
                                                    const float* __restrict__ bias, int Kdim,
                                                    int Ntiles, unsigned short* __restrict__ q_out,
                                                    unsigned short* __restrict__ k_out,
                                                    unsigned short* __restrict__ v_out,
                                                    float* __restrict__ f_out) {
  __shared__ union {
    struct { unsigned short A[2][128][40], B[2][128][40]; } s;  // 40 KB
    unsigned short T[64][136];                                  // V-transpose staging
  } u;

  const int t = threadIdx.x;
  const int lane = t & 63, w = t >> 6, ln = lane & 15, quad = lane >> 4;
  // XCD-local mt grouping (round-robin blk->XCD assumed; speed-only heuristic)
  const int xcd = blockIdx.x & 7, loc = blockIdx.x >> 3;
  const int mt = xcd * ((gridDim.x >> 3) / Ntiles) + loc / Ntiles;
  const int nt = loc % Ntiles;
  const int wm = (w >> 1) * 64, wn = (w & 1) * 64;
  const int strow = t >> 2, stcol = (t & 3) * 8;

  const size_t abase = (size_t)(mt * 128 + strow) * Kdim + stcol;
  const size_t bbase = (size_t)(nt * 128 + strow) * Kdim + stcol;

  f32x4 acc[4][4];
#pragma unroll
  for (int i = 0; i < 4; ++i)
#pragma unroll
    for (int j = 0; j < 4; ++j) acc[i][j] = (f32x4){0.f, 0.f, 0.f, 0.f};

  // prologue: load + stage chunk 0 into buf 0
  bf16x8 a0 = *(const bf16x8*)(A + abase);
  bf16x8 a1 = *(const bf16x8*)(A + abase + (size_t)64 * Kdim);
  bf16x8 b0 = *(const bf16x8*)(Bt + bbase);
  bf16x8 b1 = *(const bf16x8*)(Bt + bbase + (size_t)64 * Kdim);
  *(bf16x8*)&u.s.A[0][strow][stcol] = a0;
  *(bf16x8*)&u.s.A[0][64 + strow][stcol] = a1;
  *(bf16x8*)&u.s.B[0][strow][stcol] = b0;
  *(bf16x8*)&u.s.B[0][64 + strow][stcol] = b1;
  __syncthreads();

  const int iters = Kdim >> 5;
  for (int it = 0; it < iters; ++it) {
    const int cur = it & 1, nxt = cur ^ 1;

    // issue next-chunk loads FIRST (drained at the LDS write below)
    const int kn = ((it + 1) << 5) & (Kdim - 1);
    a0 = *(const bf16x8*)(A + abase + kn);
    a1 = *(const bf16x8*)(A + abase + (size_t)64 * Kdim + kn);
    b0 = *(const bf16x8*)(Bt + bbase + kn);
    b1 = *(const bf16x8*)(Bt + bbase + (size_t)64 * Kdim + kn);

    bf16x8 bfr[4];
#pragma unroll
    for (int nf = 0; nf < 4; ++nf)
      bfr[nf] = *(const bf16x8*)&u.s.B[cur][wn + nf * 16 + ln][quad * 8];
#pragma unroll
    for (int mf = 0; mf < 4; ++mf) {
      bf16x8 af = *(const bf16x8*)&u.s.A[cur][wm + mf * 16 + ln][quad * 8];
#pragma unroll
      for (int nf = 0; nf < 4; ++nf)
        acc[mf][nf] = __builtin_amdgcn_mfma_f32_16x16x32_bf16(af, bfr[nf], acc[mf][nf], 0, 0, 0);
    }

    if (it + 1 < iters) {
      *(bf16x8*)&u.s.A[nxt][strow][stcol] = a0;
      *(bf16x8*)&u.s.A[nxt][64 + strow][stcol] = a1;
      *(bf16x8*)&u.s.B[nxt][strow][stcol] = b0;
      *(bf16x8*)&u.s.B[nxt][64 + strow][stcol] = b1;
      __syncthreads();
    }
  }

  // ---------------- epilogue (C layout: col=lane&15, row=quad*4+reg) ----------
  if (MODE == 0 && nt >= 8) {
    // V: LDS transpose -> coalesced V^T rows. Tile = 128 s x 128 d-cols.
    const int bb = mt >> 4, sq0 = (mt & 15) * 128;
#pragma unroll
    for (int half = 0; half < 2; ++half) {
      __syncthreads();  // A/B buffers dead; T aliases them
      if ((w & 1) == half) {
#pragma unroll
        for (int nf = 0; nf < 4; ++nf) {
          const float bv = bias[nt * 128 + half * 64 + nf * 16 + ln];
#pragma unroll
          for (int mf = 0; mf < 4; ++mf)
#pragma unroll
            for (int r = 0; r < 4; ++r)
              u.T[nf * 16 + ln][wm + mf * 16 + quad * 4 + r] = f2h(acc[mf][nf][r] + bv);
        }
      }
      __syncthreads();
#pragma unroll
      for (int rep = 0; rep < 4; ++rep) {
        const int row = rep * 16 + (t >> 4), c = t & 15;
        const bf16x8 val = *(const bf16x8*)&u.T[row][c * 8];
        const int hd = (nt - 8) * 128 + half * 64 + row;
        const int hh = hd >> 6, dd = hd & 63;
        *(bf16x8*)(v_out + ((size_t)(bb * 8 + hh) * 64 + dd) * 2048 + sq0 + c * 8) = val;
      }
    }
    return;
  }

#pragma unroll
  for (int mf = 0; mf < 4; ++mf) {
    const int m = mt * 128 + wm + mf * 16 + quad * 4;
#pragma unroll
    for (int nf = 0; nf < 4; ++nf) {
      const int n = nt * 128 + wn + nf * 16 + ln;
      const float bv = bias[n];
      if (MODE == 0) {
        const int hd = n & 511;
        const int hh = hd >> 6, dd = hd & 63;
        const int bb = m >> 11, sq = m & 2047;
        if (n < 512) {
#pragma unroll
          for (int r = 0; r < 4; ++r)
            q_out[((size_t)(bb * 8 + hh) * 2048 + sq + r) * 64 + dd] =
                f2bf((acc[mf][nf][r] + bv) * QSCALE);
        } else {
#pragma unroll
          for (int r = 0; r < 4; ++r)
            k_out[((size_t)(bb * 8 + hh) * 2048 + sq + r) * 64 + dd] = f2bf(acc[mf][nf][r] + bv);
        }
      } else {
#pragma unroll
        for (int r = 0; r < 4; ++r) f_out[(size_t)(m + r) * 512 + n] = acc[mf][nf][r] + bv;
      }
    }
  }
}

// ---------------- fused flash attention, S^T orientation, LDS-free ----------
// grid 512: bh = blk&31, qt = blk>>5. 4 waves x 32 q-rows, BN=64, no LDS,
// no barriers. All fragments read directly from global (L2-resident streams;
// K-frag & V-frag instrs are 1KB-coalesced). Permuted key mapping: QK^T
// K-frag (h,e) reads key rows h*32 + kperm + e*4 so C rows land in the
// 16x16x32 A-slot order. PV: 2h x 2qg x (4dg+ones) = 20 MFMA.
__global__ __launch_bounds__(256, 2) void attn_k(const unsigned short* __restrict__ Qg,
                                                 const unsigned short* __restrict__ Kg,
                                                 const unsigned short* __restrict__ Vg,
                                                 const unsigned long long* __restrict__ Mg,
                                                 unsigned short* __restrict__ Og) {
  const int t = threadIdx.x;
  const int w = t >> 6, lane = t & 63, ln = lane & 15, quad = lane >> 4;
  const int bh = blockIdx.x & 31, qt = blockIdx.x >> 5, bb = bh >> 3;
  const int sbase = qt * 128;

  const unsigned short* Qp = Qg + (size_t)bh * (2048 * 64);
  const unsigned short* Kp = Kg + (size_t)bh * (2048 * 64);
  const unsigned short* Vp = Vg + (size_t)bh * (64 * 2048);

  bf16x8 qf[2][2];
#pragma unroll
  for (int qg = 0; qg < 2; ++qg) {
    const int qrow = sbase + w * 32 + qg * 16 + ln;
    qf[qg][0] = *(const bf16x8*)(Qp + (size_t)qrow * 64 + quad * 8);
    qf[qg][1] = *(const bf16x8*)(Qp + (size_t)qrow * 64 + 32 + quad * 8);
  }

  // ones B-frag (K=32): B[k][n]=1 iff n==0 -> lane ln==0 holds 8 ones
  const _Float16 one_h = (_Float16)((ln == 0) ? 1.0f : 0.0f);
  const f16x8 vf_one = (f16x8){one_h, one_h, one_h, one_h, one_h, one_h, one_h, one_h};

  f32x4 acc_o[2][4];
#pragma unroll
  for (int qg = 0; qg < 2; ++qg)
#pragma unroll
    for (int dg = 0; dg < 4; ++dg) acc_o[qg][dg] = (f32x4){0.f, 0.f, 0.f, 0.f};
  f32x4 acc_1[2] = {(f32x4){0.f, 0.f, 0.f, 0.f}, (f32x4){0.f, 0.f, 0.f, 0.f}};

  const int kperm = ((ln >> 2) << 3) + (ln & 3);  // permuted K row base

  // per-lane global fragment pointers (advanced each kt)
  const unsigned short* kh0 = Kp + (size_t)kperm * 64 + quad * 8;          // h=0
  const unsigned short* kh1 = kh0 + 2048;                                  // h=1 (+32 rows)
  const unsigned short* vb0 = Vp + (size_t)(0 * 16 + ln) * 2048 + quad * 8;
  const unsigned short* vb1 = Vp + (size_t)(1 * 16 + ln) * 2048 + quad * 8;
  const unsigned short* vb2 = Vp + (size_t)(2 * 16 + ln) * 2048 + quad * 8;
  const unsigned long long* mb = Mg + (size_t)bb * 65536 + sbase + w * 32 + ln;
  const unsigned short* vb3 = Vp + (size_t)(3 * 16 + ln) * 2048 + quad * 8;

  for (int kt = 0; kt < 32; ++kt) {
    // K frags [h][e][half]: rows h*32 + kperm + e*4, cols quad*8 (+32)
    bf16x8 kf000 = *(const bf16x8*)(kh0);
    bf16x8 kf001 = *(const bf16x8*)(kh0 + 32);
    bf16x8 kf010 = *(const bf16x8*)(kh0 + 256);
    bf16x8 kf011 = *(const bf16x8*)(kh0 + 288);
    bf16x8 kf100 = *(const bf16x8*)(kh1);
    bf16x8 kf101 = *(const bf16x8*)(kh1 + 32);
    bf16x8 kf110 = *(const bf16x8*)(kh1 + 256);
    bf16x8 kf111 = *(const bf16x8*)(kh1 + 288);
    // mask words for this wave's q-rows (per qg)
    const unsigned long long m64_0 = mb[0];
    const unsigned long long m64_1 = mb[16];
    // V frags [h][dg]: B[k=quad*8+j][n=d] = V^T[dg*16+ln][kt*64 + h*32 + quad*8]
    f16x8 vfa[2][4];
    vfa[0][0] = *(const f16x8*)(vb0);
    vfa[1][0] = *(const f16x8*)(vb0 + 32);
    vfa[0][1] = *(const f16x8*)(vb1);
    vfa[1][1] = *(const f16x8*)(vb1 + 32);
    vfa[0][2] = *(const f16x8*)(vb2);
    vfa[1][2] = *(const f16x8*)(vb2 + 32);
    vfa[0][3] = *(const f16x8*)(vb3);
    vfa[1][3] = *(const f16x8*)(vb3 + 32);

    // S^T with permuted key rows: frag f=h*2+e covers keys h*32+quad*8+e*4+r
    f32x4 sc[2][4];
#pragma unroll
    for (int qg = 0; qg < 2; ++qg) {
      f32x4 z;
      z = (f32x4){0.f, 0.f, 0.f, 0.f};
      z = __builtin_amdgcn_mfma_f32_16x16x32_bf16(kf000, qf[qg][0], z, 0, 0, 0);
      sc[qg][0] = __builtin_amdgcn_mfma_f32_16x16x32_bf16(kf001, qf[qg][1], z, 0, 0, 0);
      z = (f32x4){0.f, 0.f, 0.f, 0.f};
      z = __builtin_amdgcn_mfma_f32_16x16x32_bf16(kf010, qf[qg][0], z, 0, 0, 0);
      sc[qg][1] = __builtin_amdgcn_mfma_f32_16x16x32_bf16(kf011, qf[qg][1], z, 0, 0, 0);
      z = (f32x4){0.f, 0.f, 0.f, 0.f};
      z = __builtin_amdgcn_mfma_f32_16x16x32_bf16(kf100, qf[qg][0], z, 0, 0, 0);
      sc[qg][2] = __builtin_amdgcn_mfma_f32_16x16x32_bf16(kf101, qf[qg][1], z, 0, 0, 0);
      z = (f32x4){0.f, 0.f, 0.f, 0.f};
      z = __builtin_amdgcn_mfma_f32_16x16x32_bf16(kf110, qf[qg][0], z, 0, 0, 0);
      sc[qg][3] = __builtin_amdgcn_mfma_f32_16x16x32_bf16(kf111, qf[qg][1], z, 0, 0, 0);
    }

    // mask (sign-mask AND) + exp2 -> P in K=32 A-slot order, packed cvt
    f16x8 pa[2][2];
#pragma unroll
    for (int qg = 0; qg < 2; ++qg) {
      const unsigned long long m64 = qg ? m64_1 : m64_0;
#pragma unroll
      for (int h = 0; h < 2; ++h) {
        const unsigned wrd = (h ? (unsigned)(m64 >> 32) : (unsigned)m64) >> (quad * 8);
        float p[8];
#pragma unroll
        for (int e = 0; e < 2; ++e)
#pragma unroll
          for (int r = 0; r < 4; ++r) {
            const int j = e * 4 + r;
            const int se = sbit(wrd, j);
            const float s = __int_as_float(__float_as_int(sc[qg][h * 2 + e][r]) & se);
            p[j] = EXP2F(s);
          }
        pa[qg][h] = pk8(p);
      }
    }

    // O += P @ V (K=32) ; lsum += P @ ones (col 0 of acc_1)
#pragma unroll
    for (int h = 0; h < 2; ++h)
#pragma unroll
      for (int qg = 0; qg < 2; ++qg) {
#pragma unroll
        for (int dg = 0; dg < 4; ++dg)
          acc_o[qg][dg] = mfma_pv(pa[qg][h], vfa[h][dg], acc_o[qg][dg]);
        acc_1[qg] = mfma_pv(pa[qg][h], vf_one, acc_1[qg]);
      }

    // advance streams: K +64 rows, V^T +64 cols, M +1 kt
    kh0 += 4096; kh1 += 4096;
    vb0 += 64; vb1 += 64; vb2 += 64; vb3 += 64;
    mb += 2048;
  }

  // epilogue: lsum for row q=quad*4+r lives in acc_1[qg][r] at lanes ln==0
  unsigned short* Op = Og + (size_t)bb * 2048 * 512 + (size_t)(bh & 7) * 64;
#pragma unroll
  for (int qg = 0; qg < 2; ++qg)
#pragma unroll
    for (int r = 0; r < 4; ++r) {
      const float inv = 1.0f / __shfl(acc_1[qg][r], quad * 16);
      const int sq = sbase + w * 32 + qg * 16 + quad * 4 + r;
#pragma unroll
      for (int dg = 0; dg < 4; ++dg)
        Op[(size_t)sq * 512 + dg * 16 + ln] = f2bf(acc_o[qg][dg][r] * inv);
    }
}

// ---------------------------------------------------------------------------
extern "C" void kernel_launch(void* const* d_in, const int* in_sizes, int n_in, void* d_out,
                              int out_size, void* d_ws, size_t ws_size, hipStream_t stream) {
  const float* x = (const float*)d_in[0];
  const float* adj = (const float*)d_in[1];
  const float* wqkv = (const float*)d_in[2];
  const float* bqkv = (const float*)d_in[3];
  const float* outw = (const float*)d_in[4];
  const float* outb = (const float*)d_in[5];
  float* out = (float*)d_out;

  char* ws = (char*)d_ws;
  unsigned short* x_bf = (unsigned short*)(ws);                      //  8.0 MB
  unsigned short* wqkv_bf = (unsigned short*)(ws + 8388608);         //  1.5 MB
  unsigned short* outw_bf = (unsigned short*)(ws + 9961472);         //  0.5 MB
  unsigned long long* abits = (unsigned long long*)(ws + 10485760);  //  2.0 MB
  unsigned short* Qb = (unsigned short*)(ws + 27262976);             //  8.0 MB (b,h,s,d) bf16
  unsigned short* Kb = (unsigned short*)(ws + 35651584);             //  8.0 MB (b,h,s,d) bf16
  unsigned short* Vb = (unsigned short*)(ws + 44040192);             //  8.0 MB (b,h,d,s) f16
  unsigned short* Ob = (unsigned short*)(ws + 52428800);             //  8.0 MB (b,s,e) bf16

  prep_k<<<7168, 256, 0, stream>>>(x, x_bf, wqkv, wqkv_bf, outw, outw_bf, adj, abits);

  gemm128_k<0><<<768, 256, 0, stream>>>(x_bf, wqkv_bf, bqkv, 512, 12, Qb, Kb, Vb, nullptr);

  attn_k<<<512, 256, 0, stream>>>(Qb, Kb, Vb, abits, Ob);

  gemm128_k<1><<<256, 256, 0, stream>>>(Ob, outw_bf, outb, 512, 4, nullptr, nullptr, nullptr, out);
}

// Round 5
// 214.660 us; speedup vs baseline: 1.3498x; 1.3498x over previous
//
#include <hip/hip_runtime.h>

// ---------------------------------------------------------------------------
// MultiHeadAttention: x(4,2048,512) fp32, adj(4,2048,2048) 0/1 fp32
// R16: attn = R12 structure + 2q x 2k wave tiling. Evidence across R12-R15:
// LDS unit is ~75-100% busy (4 waves x 16 b128 frag reads/iter = 64KB/iter
// + 17KB writes vs 128B/cy), and all 4 waves read IDENTICAL fragments (frag
// addrs don't depend on w). Wave (wq,wk) now owns 64q x 32keys: per-wave
// frag reads 16 -> 8 b128 (block read traffic halves), MFMA/VALU/staging
// unchanged. acc_o becomes key-partial -> one-time cross-wave reduce via
// f32 LDS buffer (stride 68: <=2-way, free) + 1 barrier. LDS 34.8->70KB
// (still 2 blocks/CU). Swizzles identical to R12 (measured 0 conflicts).
// ---------------------------------------------------------------------------

typedef __attribute__((ext_vector_type(8))) short bf16x8;
typedef __attribute__((ext_vector_type(4))) float f32x4;
typedef __attribute__((ext_vector_type(4))) unsigned short ushort4v;
typedef __attribute__((ext_vector_type(4))) _Float16 f16x4;
typedef __attribute__((ext_vector_type(8))) _Float16 f16x8;
typedef __attribute__((ext_vector_type(2))) __fp16 h16x2;  // cvt_pkrtz return type

#if __has_builtin(__builtin_amdgcn_exp2f)
#define EXP2F(x) __builtin_amdgcn_exp2f(x)
#else
#define EXP2F(x) exp2f(x)
#endif

// 0.125 (1/sqrt(64)) * log2(e), folded into Q at the QKV-gemm epilogue
#define QSCALE 0.18033688011112042f

__device__ __forceinline__ unsigned short f2bf(float f) {
  unsigned int u = __float_as_uint(f);
  u += 0x7FFFu + ((u >> 16) & 1u);
  return (unsigned short)(u >> 16);
}
__device__ __forceinline__ unsigned short f2h(float f) {
  union { _Float16 h; unsigned short u; } cv;
  cv.h = (_Float16)f;
  return cv.u;
}

// sign-extend bit (pos) of w to 0 / 0xFFFFFFFF
__device__ __forceinline__ int sbit(unsigned w, int pos) {
  return ((int)(w << (31 - pos))) >> 31;  // compiler emits v_bfe_i32
}

// pack 8 floats -> f16x8 via 4 packed RTZ converts
__device__ __forceinline__ f16x8 pk8(const float* p) {
  union { struct { h16x2 a, b, c, d; } s; f16x8 v; } u;
  u.s.a = __builtin_amdgcn_cvt_pkrtz(p[0], p[1]);
  u.s.b = __builtin_amdgcn_cvt_pkrtz(p[2], p[3]);
  u.s.c = __builtin_amdgcn_cvt_pkrtz(p[4], p[5]);
  u.s.d = __builtin_amdgcn_cvt_pkrtz(p[6], p[7]);
  return u.v;
}

// PV matmul: K=32 f16 (slot pairing identical in A and B, so a two-K=16
// fallback is mathematically identical if the builtin is absent)
__device__ __forceinline__ f32x4 mfma_pv(f16x8 a, f16x8 b, f32x4 c) {
#if __has_builtin(__builtin_amdgcn_mfma_f32_16x16x32_f16)
  return __builtin_amdgcn_mfma_f32_16x16x32_f16(a, b, c, 0, 0, 0);
#else
  union { f16x8 v; struct { f16x4 lo, hi; } s; } ua, ub;
  ua.v = a; ub.v = b;
  c = __builtin_amdgcn_mfma_f32_16x16x16f16(ua.s.lo, ub.s.lo, c, 0, 0, 0);
  return __builtin_amdgcn_mfma_f32_16x16x16f16(ua.s.hi, ub.s.hi, c, 0, 0, 0);
#endif
}

// ---------------- fused prep: casts + adj bit-pack, one launch ---------------
__global__ __launch_bounds__(256) void prep_k(const float* __restrict__ x,
                                              unsigned short* __restrict__ x_bf,
                                              const float* __restrict__ wqkv,
                                              unsigned short* __restrict__ wqkv_bf,
                                              const float* __restrict__ outw,
                                              unsigned short* __restrict__ outw_bf,
                                              const float* __restrict__ adj,
                                              unsigned long long* __restrict__ abits) {
  const int bid = blockIdx.x;
  if (bid < 5120) {
    const float* in; unsigned short* out; int i;
    if (bid < 4096) { in = x; out = x_bf; i = bid * 256 + threadIdx.x; }
    else if (bid < 4864) { in = wqkv; out = wqkv_bf; i = (bid - 4096) * 256 + threadIdx.x; }
    else { in = outw; out = outw_bf; i = (bid - 4864) * 256 + threadIdx.x; }
    float4 v = ((const float4*)in)[i];
    ushort4v o;
    o[0] = f2bf(v.x); o[1] = f2bf(v.y); o[2] = f2bf(v.z); o[3] = f2bf(v.w);
    ((ushort4v*)out)[i] = o;
  } else {
    const int gw = (bid - 5120) * 4 + (threadIdx.x >> 6);  // 0..8191 = b*2048+q
    const int l = threadIdx.x & 63;
    const int b = gw >> 11, q = gw & 2047;
    const float* row = adj + ((size_t)b * 2048 + q) * 2048;
    unsigned long long* ob = abits + (size_t)b * 65536 + q;
#pragma unroll 4
    for (int kt = 0; kt < 32; ++kt) {
      const float v = row[kt * 64 + l];
      const unsigned long long m = __ballot(v != 0.f);
      if (l == 0) ob[(size_t)kt * 2048] = m;
    }
  }
}

// ---------------- 128x128 bf16 MFMA GEMM: C = A @ Bt^T (+bias) ----------------
// XCD-local tiling: blk&7 = XCD; each XCD owns a contiguous mt range so its
// L2 reuses A rows across all nt. Double-buffered LDS, one barrier/iter.
// MODE 0: QKV epilogue (Q scaled bf16 / K bf16 / V f16 LDS-transposed).
// MODE 1: fp32 + bias epilogue to f_out
template <int MODE>
__global__ __launch_bounds__(256, 3) void gemm128_k(const unsigned short* __restrict__ A,
                                                    const unsigned short* __restrict__ Bt,
                                                    const float* __restrict__ bias, int Kdim,
                                                    int Ntiles, unsigned short* __restrict__ q_out,
                                                    unsigned short* __restrict__ k_out,
                                                    unsigned short* __restrict__ v_out,
                                                    float* __restrict__ f_out) {
  __shared__ union {
    struct { unsigned short A[2][128][40], B[2][128][40]; } s;  // 40 KB
    unsigned short T[64][136];                                  // V-transpose staging
  } u;

  const int t = threadIdx.x;
  const int lane = t & 63, w = t >> 6, ln = lane & 15, quad = lane >> 4;
  // XCD-local mt grouping (round-robin blk->XCD assumed; speed-only heuristic)
  const int xcd = blockIdx.x & 7, loc = blockIdx.x >> 3;
  const int mt = xcd * ((gridDim.x >> 3) / Ntiles) + loc / Ntiles;
  const int nt = loc % Ntiles;
  const int wm = (w >> 1) * 64, wn = (w & 1) * 64;
  const int strow = t >> 2, stcol = (t & 3) * 8;

  const size_t abase = (size_t)(mt * 128 + strow) * Kdim + stcol;
  const size_t bbase = (size_t)(nt * 128 + strow) * Kdim + stcol;

  f32x4 acc[4][4];
#pragma unroll
  for (int i = 0; i < 4; ++i)
#pragma unroll
    for (int j = 0; j < 4; ++j) acc[i][j] = (f32x4){0.f, 0.f, 0.f, 0.f};

  // prologue: load + stage chunk 0 into buf 0
  bf16x8 a0 = *(const bf16x8*)(A + abase);
  bf16x8 a1 = *(const bf16x8*)(A + abase + (size_t)64 * Kdim);
  bf16x8 b0 = *(const bf16x8*)(Bt + bbase);
  bf16x8 b1 = *(const bf16x8*)(Bt + bbase + (size_t)64 * Kdim);
  *(bf16x8*)&u.s.A[0][strow][stcol] = a0;
  *(bf16x8*)&u.s.A[0][64 + strow][stcol] = a1;
  *(bf16x8*)&u.s.B[0][strow][stcol] = b0;
  *(bf16x8*)&u.s.B[0][64 + strow][stcol] = b1;
  __syncthreads();

  const int iters = Kdim >> 5;
  for (int it = 0; it < iters; ++it) {
    const int cur = it & 1, nxt = cur ^ 1;

    // issue next-chunk loads FIRST (drained at the LDS write below)
    const int kn = ((it + 1) << 5) & (Kdim - 1);
    a0 = *(const bf16x8*)(A + abase + kn);
    a1 = *(const bf16x8*)(A + abase + (size_t)64 * Kdim + kn);
    b0 = *(const bf16x8*)(Bt + bbase + kn);
    b1 = *(const bf16x8*)(Bt + bbase + (size_t)64 * Kdim + kn);

    bf16x8 bfr[4];
#pragma unroll
    for (int nf = 0; nf < 4; ++nf)
      bfr[nf] = *(const bf16x8*)&u.s.B[cur][wn + nf * 16 + ln][quad * 8];
#pragma unroll
    for (int mf = 0; mf < 4; ++mf) {
      bf16x8 af = *(const bf16x8*)&u.s.A[cur][wm + mf * 16 + ln][quad * 8];
#pragma unroll
      for (int nf = 0; nf < 4; ++nf)
        acc[mf][nf] = __builtin_amdgcn_mfma_f32_16x16x32_bf16(af, bfr[nf], acc[mf][nf], 0, 0, 0);
    }

    if (it + 1 < iters) {
      *(bf16x8*)&u.s.A[nxt][strow][stcol] = a0;
      *(bf16x8*)&u.s.A[nxt][64 + strow][stcol] = a1;
      *(bf16x8*)&u.s.B[nxt][strow][stcol] = b0;
      *(bf16x8*)&u.s.B[nxt][64 + strow][stcol] = b1;
      __syncthreads();
    }
  }

  // ---------------- epilogue (C layout: col=lane&15, row=quad*4+reg) ----------
  if (MODE == 0 && nt >= 8) {
    // V: LDS transpose -> coalesced V^T rows. Tile = 128 s x 128 d-cols.
    const int bb = mt >> 4, sq0 = (mt & 15) * 128;
#pragma unroll
    for (int half = 0; half < 2; ++half) {
      __syncthreads();  // A/B buffers dead; T aliases them
      if ((w & 1) == half) {
#pragma unroll
        for (int nf = 0; nf < 4; ++nf) {
          const float bv = bias[nt * 128 + half * 64 + nf * 16 + ln];
#pragma unroll
          for (int mf = 0; mf < 4; ++mf)
#pragma unroll
            for (int r = 0; r < 4; ++r)
              u.T[nf * 16 + ln][wm + mf * 16 + quad * 4 + r] = f2h(acc[mf][nf][r] + bv);
        }
      }
      __syncthreads();
#pragma unroll
      for (int rep = 0; rep < 4; ++rep) {
        const int row = rep * 16 + (t >> 4), c = t & 15;
        const bf16x8 val = *(const bf16x8*)&u.T[row][c * 8];
        const int hd = (nt - 8) * 128 + half * 64 + row;
        const int hh = hd >> 6, dd = hd & 63;
        *(bf16x8*)(v_out + ((size_t)(bb * 8 + hh) * 64 + dd) * 2048 + sq0 + c * 8) = val;
      }
    }
    return;
  }

#pragma unroll
  for (int mf = 0; mf < 4; ++mf) {
    const int m = mt * 128 + wm + mf * 16 + quad * 4;
#pragma unroll
    for (int nf = 0; nf < 4; ++nf) {
      const int n = nt * 128 + wn + nf * 16 + ln;
      const float bv = bias[n];
      if (MODE == 0) {
        const int hd = n & 511;
        const int hh = hd >> 6, dd = hd & 63;
        const int bb = m >> 11, sq = m & 2047;
        if (n < 512) {
#pragma unroll
          for (int r = 0; r < 4; ++r)
            q_out[((size_t)(bb * 8 + hh) * 2048 + sq + r) * 64 + dd] =
                f2bf((acc[mf][nf][r] + bv) * QSCALE);
        } else {
#pragma unroll
          for (int r = 0; r < 4; ++r)
            k_out[((size_t)(bb * 8 + hh) * 2048 + sq + r) * 64 + dd] = f2bf(acc[mf][nf][r] + bv);
        }
      } else {
#pragma unroll
        for (int r = 0; r < 4; ++r) f_out[(size_t)(m + r) * 512 + n] = acc[mf][nf][r] + bv;
      }
    }
  }
}

// ---------------- fused flash attention, S^T orientation, 2q x 2k waves -----
// grid 512: bh = blk&31, qt = blk>>5. Wave (wq=w&1, wk=w>>1) owns 64 q-rows
// x 32 keys -> per-wave frag reads halve (4 kf + 4 vfa b128/iter) vs all-q
// waves; MFMA/VALU/staging work unchanged. acc_o/acc_1 are key-partial;
// wk=1 deposits to f32 LDS (stride 68, <=2-way free), wk=0 combines,
// normalizes, stores. Permuted key mapping + chunk swizzles = R12.
__global__ __launch_bounds__(256, 2) void attn_k(const unsigned short* __restrict__ Qg,
                                                 const unsigned short* __restrict__ Kg,
                                                 const unsigned short* __restrict__ Vg,
                                                 const unsigned long long* __restrict__ Mg,
                                                 unsigned short* __restrict__ Og) {
  __shared__ unsigned short K_lds[2][64][64];   // [buf][key][d] bf16, chunk-swizzled
  __shared__ unsigned short V_lds[2][64][64];   // [buf][d][key] f16, chunk-swizzled
  __shared__ unsigned long long M_lds[2][128];  // [buf][q] mask bits
  __shared__ float Rf[128][68];                 // key-reduce buffer (34 KB)
  __shared__ float Rl[128];                     // lsum partials (wk=1)

  const int t = threadIdx.x;
  const int w = t >> 6, lane = t & 63, ln = lane & 15, quad = lane >> 4;
  const int wq = w & 1, wk = w >> 1;  // q-half, key-half
  const int bh = blockIdx.x & 31, qt = blockIdx.x >> 5, bb = bh >> 3;
  const int sbase = qt * 128;

  const unsigned short* Qp = Qg + (size_t)bh * (2048 * 64);
  const unsigned short* Kp = Kg + (size_t)bh * (2048 * 64);
  const unsigned short* Vp = Vg + (size_t)bh * (64 * 2048);
  const unsigned long long* Mp = Mg + (size_t)bb * 65536 + sbase;

  bf16x8 qf[4][2];
#pragma unroll
  for (int qg = 0; qg < 4; ++qg) {
    const int qrow = sbase + wq * 64 + qg * 16 + ln;
    qf[qg][0] = *(const bf16x8*)(Qp + (size_t)qrow * 64 + quad * 8);
    qf[qg][1] = *(const bf16x8*)(Qp + (size_t)qrow * 64 + 32 + quad * 8);
  }

  // ones B-frag (K=32): B[k][n]=1 iff n==0 -> lane ln==0 holds 8 ones
  const _Float16 one_h = (_Float16)((ln == 0) ? 1.0f : 0.0f);
  const f16x8 vf_one = (f16x8){one_h, one_h, one_h, one_h, one_h, one_h, one_h, one_h};

  f32x4 acc_o[4][4];
#pragma unroll
  for (int qg = 0; qg < 4; ++qg)
#pragma unroll
    for (int dg = 0; dg < 4; ++dg) acc_o[qg][dg] = (f32x4){0.f, 0.f, 0.f, 0.f};
  f32x4 acc_1[4];
#pragma unroll
  for (int qg = 0; qg < 4; ++qg) acc_1[qg] = (f32x4){0.f, 0.f, 0.f, 0.f};

  const int strow = t >> 2;
  const int stcol = (t & 3) * 16;       // global column base (ushorts)
  const int c0 = (t & 3) * 2;           // LDS chunk index (16B units), even
  const int gkw = (strow & 3) | (((strow >> 3) & 1) << 2);  // K write swizzle
  const int gvw = strow & 7;                                // V write swizzle

  // per-lane base pointers (linear; last-iter prefetch reads adjacent ws)
  const unsigned short* Kl = Kp + (size_t)strow * 64 + stcol;
  const unsigned short* Vl = Vp + (size_t)strow * 2048 + stcol;

  bf16x8 kr0 = *(const bf16x8*)(Kl);
  bf16x8 kr1 = *(const bf16x8*)(Kl + 8);
  bf16x8 vr0 = *(const bf16x8*)(Vl);
  bf16x8 vr1 = *(const bf16x8*)(Vl + 8);
  unsigned long long mreg = (w < 2) ? Mp[w * 64 + lane] : 0ull;
  *(bf16x8*)&K_lds[0][strow][(c0 ^ gkw) << 3] = kr0;
  *(bf16x8*)&K_lds[0][strow][((c0 + 1) ^ gkw) << 3] = kr1;
  *(bf16x8*)&V_lds[0][strow][(c0 ^ gvw) << 3] = vr0;
  *(bf16x8*)&V_lds[0][strow][((c0 + 1) ^ gvw) << 3] = vr1;
  if (w < 2) M_lds[0][w * 64 + lane] = mreg;
  __syncthreads();

  const int mq = wq * 64 + ln;                               // M_lds row base
  const int kperm = ((ln >> 2) << 3) + (ln & 3);             // permuted K row base
  const int gkr = (ln & 3) | (((ln >> 2) & 1) << 2);         // = K swizzle of krow
  const int gvr = ln & 7;                                    // = V swizzle of vrow
  const int kc = (quad ^ gkr) << 3;                          // phys col of chunk `quad`

  for (int kt = 0; kt < 32; ++kt) {
    const int cur = kt & 1, nxt = cur ^ 1;

    // next-tile global loads, linear addressing (drained at LDS writes below)
    kr0 = *(const bf16x8*)(Kl + (size_t)(kt + 1) * 4096);
    kr1 = *(const bf16x8*)(Kl + (size_t)(kt + 1) * 4096 + 8);
    vr0 = *(const bf16x8*)(Vl + (kt + 1) * 64);
    vr1 = *(const bf16x8*)(Vl + (kt + 1) * 64 + 8);
    mreg = (w < 2) ? Mp[(size_t)(kt + 1) * 2048 + w * 64 + lane] : 0ull;

    // K frags for this wave's 32-key half: rows wk*32 + kperm + e*4
    bf16x8 kf[2][2];
#pragma unroll
    for (int e = 0; e < 2; ++e) {
      const int krow = wk * 32 + kperm + e * 4;
      kf[e][0] = *(const bf16x8*)&K_lds[cur][krow][kc];
      kf[e][1] = *(const bf16x8*)&K_lds[cur][krow][kc ^ 32];  // chunk quad+4
    }

    // S^T: frag (qg,e) covers keys wk*32+quad*8+e*4+r, q-col = wq*64+qg*16+ln
    f32x4 sc[4][2];
#pragma unroll
    for (int qg = 0; qg < 4; ++qg)
#pragma unroll
      for (int e = 0; e < 2; ++e) {
        f32x4 z = (f32x4){0.f, 0.f, 0.f, 0.f};
        z = __builtin_amdgcn_mfma_f32_16x16x32_bf16(kf[e][0], qf[qg][0], z, 0, 0, 0);
        sc[qg][e] = __builtin_amdgcn_mfma_f32_16x16x32_bf16(kf[e][1], qf[qg][1], z, 0, 0, 0);
      }

    // V frags (b128): B[k=quad*8+j][n=d] = V_lds[d][wk*32+quad*8]
    f16x8 vfa[4];
#pragma unroll
    for (int dg = 0; dg < 4; ++dg)
      vfa[dg] = *(const f16x8*)&V_lds[cur][dg * 16 + ln][((wk * 4 + quad) ^ gvr) << 3];

    // mask (sign-mask AND) + exp2 -> P in K=32 A-slot order, packed cvt
    f16x8 pa[4];
#pragma unroll
    for (int qg = 0; qg < 4; ++qg) {
      const unsigned long long m64 = M_lds[cur][mq + qg * 16];
      const unsigned wrd = (wk ? (unsigned)(m64 >> 32) : (unsigned)m64) >> (quad * 8);
      float p[8];
#pragma unroll
      for (int e = 0; e < 2; ++e)
#pragma unroll
        for (int r = 0; r < 4; ++r) {
          const int j = e * 4 + r;
          const int se = sbit(wrd, j);
          const float s = __int_as_float(__float_as_int(sc[qg][e][r]) & se);
          p[j] = EXP2F(s);
        }
      pa[qg] = pk8(p);
    }

    // O += P @ V (K=32 over this wave's 32 keys) ; lsum += P @ ones
#pragma unroll
    for (int qg = 0; qg < 4; ++qg) {
#pragma unroll
      for (int dg = 0; dg < 4; ++dg)
        acc_o[qg][dg] = mfma_pv(pa[qg], vfa[dg], acc_o[qg][dg]);
      acc_1[qg] = mfma_pv(pa[qg], vf_one, acc_1[qg]);
    }

    if (kt < 31) {
      *(bf16x8*)&K_lds[nxt][strow][(c0 ^ gkw) << 3] = kr0;
      *(bf16x8*)&K_lds[nxt][strow][((c0 + 1) ^ gkw) << 3] = kr1;
      *(bf16x8*)&V_lds[nxt][strow][(c0 ^ gvw) << 3] = vr0;
      *(bf16x8*)&V_lds[nxt][strow][((c0 + 1) ^ gvw) << 3] = vr1;
      if (w < 2) M_lds[nxt][w * 64 + lane] = mreg;
      __syncthreads();
    }
  }

  // cross-wave key reduce: wk=1 deposits f32 partials, wk=0 combines+stores.
  // C layout: row (q within qg*16) = quad*4+r, col (d within dg*16) = ln.
  if (wk == 1) {
#pragma unroll
    for (int qg = 0; qg < 4; ++qg)
#pragma unroll
      for (int r = 0; r < 4; ++r) {
        const int q = wq * 64 + qg * 16 + quad * 4 + r;
        if (ln == 0) Rl[q] = acc_1[qg][r];
#pragma unroll
        for (int dg = 0; dg < 4; ++dg) Rf[q][dg * 16 + ln] = acc_o[qg][dg][r];
      }
  }
  __syncthreads();
  if (wk == 0) {
    unsigned short* Op = Og + (size_t)bb * 2048 * 512 + (size_t)(bh & 7) * 64;
#pragma unroll
    for (int qg = 0; qg < 4; ++qg)
#pragma unroll
      for (int r = 0; r < 4; ++r) {
        const int q = wq * 64 + qg * 16 + quad * 4 + r;
        const float inv = 1.0f / (__shfl(acc_1[qg][r], quad * 16) + Rl[q]);
        const int sq = sbase + q;
#pragma unroll
        for (int dg = 0; dg < 4; ++dg)
          Op[(size_t)sq * 512 + dg * 16 + ln] =
              f2bf((acc_o[qg][dg][r] + Rf[q][dg * 16 + ln]) * inv);
      }
  }
}

// ---------------------------------------------------------------------------
extern "C" void kernel_launch(void* const* d_in, const int* in_sizes, int n_in, void* d_out,
                              int out_size, void* d_ws, size_t ws_size, hipStream_t stream) {
  const float* x = (const float*)d_in[0];
  const float* adj = (const float*)d_in[1];
  const float* wqkv = (const float*)d_in[2];
  const float* bqkv = (const float*)d_in[3];
  const float* outw = (const float*)d_in[4];
  const float* outb = (const float*)d_in[5];
  float* out = (float*)d_out;

  char* ws = (char*)d_ws;
  unsigned short* x_bf = (unsigned short*)(ws);                      //  8.0 MB
  unsigned short* wqkv_bf = (unsigned short*)(ws + 8388608);         //  1.5 MB
  unsigned short* outw_bf = (unsigned short*)(ws + 9961472);         //  0.5 MB
  unsigned long long* abits = (unsigned long long*)(ws + 10485760);  //  2.0 MB
  unsigned short* Qb = (unsigned short*)(ws + 27262976);             //  8.0 MB (b,h,s,d) bf16
  unsigned short* Kb = (unsigned short*)(ws + 35651584);             //  8.0 MB (b,h,s,d) bf16
  unsigned short* Vb = (unsigned short*)(ws + 44040192);             //  8.0 MB (b,h,d,s) f16
  unsigned short* Ob = (unsigned short*)(ws + 52428800);             //  8.0 MB (b,s,e) bf16

  prep_k<<<7168, 256, 0, stream>>>(x, x_bf, wqkv, wqkv_bf, outw, outw_bf, adj, abits);

  gemm128_k<0><<<768, 256, 0, stream>>>(x_bf, wqkv_bf, bqkv, 512, 12, Qb, Kb, Vb, nullptr);

  attn_k<<<512, 256, 0, stream>>>(Qb, Kb, Vb, abits, Ob);

  gemm128_k<1><<<256, 256, 0, stream>>>(Ob, outw_bf, outb, 512, 4, nullptr, nullptr, nullptr, out);
}

// Round 6
// 210.665 us; speedup vs baseline: 1.3754x; 1.0190x over previous
//
#include <hip/hip_runtime.h>

// ---------------------------------------------------------------------------
// MultiHeadAttention: x(4,2048,512) fp32, adj(4,2048,2048) 0/1 fp32
// R17: R12 attn structure (best measured) + issue-chain diet. Evidence
// R12-R16: kernel is issue-bound (~830cy VALU + ~540cy MFMA + ~550cy idle
// per wave-iter, invariant under occupancy/traffic changes). Cuts:
//  - hoisted zero f32x4 as QK MFMA C-operand (kills 32 v_mov/iter)
//  - masks read directly from global per wave (prefetched; kills M_lds
//    writes/reads + w<2 branches, -2KB LDS)
//  - #pragma unroll 2 folds dbuf cur/nxt into LDS address immediates
//  - s_setprio(1) around MFMA clusters (T5; 2 indep blocks/CU)
// K/V staging + chunk swizzles identical to R12 (measured 0 conflicts).
// ---------------------------------------------------------------------------

typedef __attribute__((ext_vector_type(8))) short bf16x8;
typedef __attribute__((ext_vector_type(4))) float f32x4;
typedef __attribute__((ext_vector_type(4))) unsigned short ushort4v;
typedef __attribute__((ext_vector_type(4))) _Float16 f16x4;
typedef __attribute__((ext_vector_type(8))) _Float16 f16x8;
typedef __attribute__((ext_vector_type(2))) __fp16 h16x2;  // cvt_pkrtz return type

#if __has_builtin(__builtin_amdgcn_exp2f)
#define EXP2F(x) __builtin_amdgcn_exp2f(x)
#else
#define EXP2F(x) exp2f(x)
#endif

// 0.125 (1/sqrt(64)) * log2(e), folded into Q at the QKV-gemm epilogue
#define QSCALE 0.18033688011112042f

__device__ __forceinline__ unsigned short f2bf(float f) {
  unsigned int u = __float_as_uint(f);
  u += 0x7FFFu + ((u >> 16) & 1u);
  return (unsigned short)(u >> 16);
}
__device__ __forceinline__ unsigned short f2h(float f) {
  union { _Float16 h; unsigned short u; } cv;
  cv.h = (_Float16)f;
  return cv.u;
}

// sign-extend bit (pos) of w to 0 / 0xFFFFFFFF
__device__ __forceinline__ int sbit(unsigned w, int pos) {
  return ((int)(w << (31 - pos))) >> 31;  // compiler emits v_bfe_i32
}

// pack 8 floats -> f16x8 via 4 packed RTZ converts
__device__ __forceinline__ f16x8 pk8(const float* p) {
  union { struct { h16x2 a, b, c, d; } s; f16x8 v; } u;
  u.s.a = __builtin_amdgcn_cvt_pkrtz(p[0], p[1]);
  u.s.b = __builtin_amdgcn_cvt_pkrtz(p[2], p[3]);
  u.s.c = __builtin_amdgcn_cvt_pkrtz(p[4], p[5]);
  u.s.d = __builtin_amdgcn_cvt_pkrtz(p[6], p[7]);
  return u.v;
}

// PV matmul: K=32 f16 (slot pairing identical in A and B, so a two-K=16
// fallback is mathematically identical if the builtin is absent)
__device__ __forceinline__ f32x4 mfma_pv(f16x8 a, f16x8 b, f32x4 c) {
#if __has_builtin(__builtin_amdgcn_mfma_f32_16x16x32_f16)
  return __builtin_amdgcn_mfma_f32_16x16x32_f16(a, b, c, 0, 0, 0);
#else
  union { f16x8 v; struct { f16x4 lo, hi; } s; } ua, ub;
  ua.v = a; ub.v = b;
  c = __builtin_amdgcn_mfma_f32_16x16x16f16(ua.s.lo, ub.s.lo, c, 0, 0, 0);
  return __builtin_amdgcn_mfma_f32_16x16x16f16(ua.s.hi, ub.s.hi, c, 0, 0, 0);
#endif
}

// ---------------- fused prep: casts + adj bit-pack, one launch ---------------
__global__ __launch_bounds__(256) void prep_k(const float* __restrict__ x,
                                              unsigned short* __restrict__ x_bf,
                                              const float* __restrict__ wqkv,
                                              unsigned short* __restrict__ wqkv_bf,
                                              const float* __restrict__ outw,
                                              unsigned short* __restrict__ outw_bf,
                                              const float* __restrict__ adj,
                                              unsigned long long* __restrict__ abits) {
  const int bid = blockIdx.x;
  if (bid < 5120) {
    const float* in; unsigned short* out; int i;
    if (bid < 4096) { in = x; out = x_bf; i = bid * 256 + threadIdx.x; }
    else if (bid < 4864) { in = wqkv; out = wqkv_bf; i = (bid - 4096) * 256 + threadIdx.x; }
    else { in = outw; out = outw_bf; i = (bid - 4864) * 256 + threadIdx.x; }
    float4 v = ((const float4*)in)[i];
    ushort4v o;
    o[0] = f2bf(v.x); o[1] = f2bf(v.y); o[2] = f2bf(v.z); o[3] = f2bf(v.w);
    ((ushort4v*)out)[i] = o;
  } else {
    const int gw = (bid - 5120) * 4 + (threadIdx.x >> 6);  // 0..8191 = b*2048+q
    const int l = threadIdx.x & 63;
    const int b = gw >> 11, q = gw & 2047;
    const float* row = adj + ((size_t)b * 2048 + q) * 2048;
    unsigned long long* ob = abits + (size_t)b * 65536 + q;
#pragma unroll 4
    for (int kt = 0; kt < 32; ++kt) {
      const float v = row[kt * 64 + l];
      const unsigned long long m = __ballot(v != 0.f);
      if (l == 0) ob[(size_t)kt * 2048] = m;
    }
  }
}

// ---------------- 128x128 bf16 MFMA GEMM: C = A @ Bt^T (+bias) ----------------
// XCD-local tiling: blk&7 = XCD; each XCD owns a contiguous mt range so its
// L2 reuses A rows across all nt. Double-buffered LDS, one barrier/iter.
// MODE 0: QKV epilogue (Q scaled bf16 / K bf16 / V f16 LDS-transposed).
// MODE 1: fp32 + bias epilogue to f_out
template <int MODE>
__global__ __launch_bounds__(256, 3) void gemm128_k(const unsigned short* __restrict__ A,
                                                    const unsigned short* __restrict__ Bt,
                                                    const float* __restrict__ bias, int Kdim,
                                                    int Ntiles, unsigned short* __restrict__ q_out,
                                                    unsigned short* __restrict__ k_out,
                                                    unsigned short* __restrict__ v_out,
                                                    float* __restrict__ f_out) {
  __shared__ union {
    struct { unsigned short A[2][128][40], B[2][128][40]; } s;  // 40 KB
    unsigned short T[64][136];                                  // V-transpose staging
  } u;

  const int t = threadIdx.x;
  const int lane = t & 63, w = t >> 6, ln = lane & 15, quad = lane >> 4;
  // XCD-local mt grouping (round-robin blk->XCD assumed; speed-only heuristic)
  const int xcd = blockIdx.x & 7, loc = blockIdx.x >> 3;
  const int mt = xcd * ((gridDim.x >> 3) / Ntiles) + loc / Ntiles;
  const int nt = loc % Ntiles;
  const int wm = (w >> 1) * 64, wn = (w & 1) * 64;
  const int strow = t >> 2, stcol = (t & 3) * 8;

  const size_t abase = (size_t)(mt * 128 + strow) * Kdim + stcol;
  const size_t bbase = (size_t)(nt * 128 + strow) * Kdim + stcol;

  f32x4 acc[4][4];
#pragma unroll
  for (int i = 0; i < 4; ++i)
#pragma unroll
    for (int j = 0; j < 4; ++j) acc[i][j] = (f32x4){0.f, 0.f, 0.f, 0.f};

  // prologue: load + stage chunk 0 into buf 0
  bf16x8 a0 = *(const bf16x8*)(A + abase);
  bf16x8 a1 = *(const bf16x8*)(A + abase + (size_t)64 * Kdim);
  bf16x8 b0 = *(const bf16x8*)(Bt + bbase);
  bf16x8 b1 = *(const bf16x8*)(Bt + bbase + (size_t)64 * Kdim);
  *(bf16x8*)&u.s.A[0][strow][stcol] = a0;
  *(bf16x8*)&u.s.A[0][64 + strow][stcol] = a1;
  *(bf16x8*)&u.s.B[0][strow][stcol] = b0;
  *(bf16x8*)&u.s.B[0][64 + strow][stcol] = b1;
  __syncthreads();

  const int iters = Kdim >> 5;
  for (int it = 0; it < iters; ++it) {
    const int cur = it & 1, nxt = cur ^ 1;

    // issue next-chunk loads FIRST (drained at the LDS write below)
    const int kn = ((it + 1) << 5) & (Kdim - 1);
    a0 = *(const bf16x8*)(A + abase + kn);
    a1 = *(const bf16x8*)(A + abase + (size_t)64 * Kdim + kn);
    b0 = *(const bf16x8*)(Bt + bbase + kn);
    b1 = *(const bf16x8*)(Bt + bbase + (size_t)64 * Kdim + kn);

    bf16x8 bfr[4];
#pragma unroll
    for (int nf = 0; nf < 4; ++nf)
      bfr[nf] = *(const bf16x8*)&u.s.B[cur][wn + nf * 16 + ln][quad * 8];
#pragma unroll
    for (int mf = 0; mf < 4; ++mf) {
      bf16x8 af = *(const bf16x8*)&u.s.A[cur][wm + mf * 16 + ln][quad * 8];
#pragma unroll
      for (int nf = 0; nf < 4; ++nf)
        acc[mf][nf] = __builtin_amdgcn_mfma_f32_16x16x32_bf16(af, bfr[nf], acc[mf][nf], 0, 0, 0);
    }

    if (it + 1 < iters) {
      *(bf16x8*)&u.s.A[nxt][strow][stcol] = a0;
      *(bf16x8*)&u.s.A[nxt][64 + strow][stcol] = a1;
      *(bf16x8*)&u.s.B[nxt][strow][stcol] = b0;
      *(bf16x8*)&u.s.B[nxt][64 + strow][stcol] = b1;
      __syncthreads();
    }
  }

  // ---------------- epilogue (C layout: col=lane&15, row=quad*4+reg) ----------
  if (MODE == 0 && nt >= 8) {
    // V: LDS transpose -> coalesced V^T rows. Tile = 128 s x 128 d-cols.
    const int bb = mt >> 4, sq0 = (mt & 15) * 128;
#pragma unroll
    for (int half = 0; half < 2; ++half) {
      __syncthreads();  // A/B buffers dead; T aliases them
      if ((w & 1) == half) {
#pragma unroll
        for (int nf = 0; nf < 4; ++nf) {
          const float bv = bias[nt * 128 + half * 64 + nf * 16 + ln];
#pragma unroll
          for (int mf = 0; mf < 4; ++mf)
#pragma unroll
            for (int r = 0; r < 4; ++r)
              u.T[nf * 16 + ln][wm + mf * 16 + quad * 4 + r] = f2h(acc[mf][nf][r] + bv);
        }
      }
      __syncthreads();
#pragma unroll
      for (int rep = 0; rep < 4; ++rep) {
        const int row = rep * 16 + (t >> 4), c = t & 15;
        const bf16x8 val = *(const bf16x8*)&u.T[row][c * 8];
        const int hd = (nt - 8) * 128 + half * 64 + row;
        const int hh = hd >> 6, dd = hd & 63;
        *(bf16x8*)(v_out + ((size_t)(bb * 8 + hh) * 64 + dd) * 2048 + sq0 + c * 8) = val;
      }
    }
    return;
  }

#pragma unroll
  for (int mf = 0; mf < 4; ++mf) {
    const int m = mt * 128 + wm + mf * 16 + quad * 4;
#pragma unroll
    for (int nf = 0; nf < 4; ++nf) {
      const int n = nt * 128 + wn + nf * 16 + ln;
      const float bv = bias[n];
      if (MODE == 0) {
        const int hd = n & 511;
        const int hh = hd >> 6, dd = hd & 63;
        const int bb = m >> 11, sq = m & 2047;
        if (n < 512) {
#pragma unroll
          for (int r = 0; r < 4; ++r)
            q_out[((size_t)(bb * 8 + hh) * 2048 + sq + r) * 64 + dd] =
                f2bf((acc[mf][nf][r] + bv) * QSCALE);
        } else {
#pragma unroll
          for (int r = 0; r < 4; ++r)
            k_out[((size_t)(bb * 8 + hh) * 2048 + sq + r) * 64 + dd] = f2bf(acc[mf][nf][r] + bv);
        }
      } else {
#pragma unroll
        for (int r = 0; r < 4; ++r) f_out[(size_t)(m + r) * 512 + n] = acc[mf][nf][r] + bv;
      }
    }
  }
}

// ---------------- fused flash attention, S^T orientation, dbuf, K=32 PV -----
// grid 512: bh = blk&31, qt = blk>>5. 4 waves x 32 q-rows, BN=64.
// Permuted key mapping: QK^T K-frag (h,e) loads K_lds row
// h*32 + kperm + e*4, so C rows hold keys h*32+quad*8+e*4+r (16x16x32 f16
// A-slot order). Masks: direct per-wave global loads, prefetched 1 iter
// ahead (no LDS). QK C-operand = hoisted zero regs. setprio around MFMA.
__global__ __launch_bounds__(256, 2) void attn_k(const unsigned short* __restrict__ Qg,
                                                 const unsigned short* __restrict__ Kg,
                                                 const unsigned short* __restrict__ Vg,
                                                 const unsigned long long* __restrict__ Mg,
                                                 unsigned short* __restrict__ Og) {
  __shared__ unsigned short K_lds[2][64][64];  // [buf][key][d] bf16, chunk-swizzled
  __shared__ unsigned short V_lds[2][64][64];  // [buf][d][key] f16, chunk-swizzled

  const int t = threadIdx.x;
  const int w = t >> 6, lane = t & 63, ln = lane & 15, quad = lane >> 4;
  const int bh = blockIdx.x & 31, qt = blockIdx.x >> 5, bb = bh >> 3;
  const int sbase = qt * 128;

  const unsigned short* Qp = Qg + (size_t)bh * (2048 * 64);
  const unsigned short* Kp = Kg + (size_t)bh * (2048 * 64);
  const unsigned short* Vp = Vg + (size_t)bh * (64 * 2048);
  // per-lane mask pointer: q-row = sbase + w*32 + ln (+16 for qg=1)
  const unsigned long long* Mw = Mg + (size_t)bb * 65536 + sbase + w * 32 + ln;

  bf16x8 qf[2][2];
#pragma unroll
  for (int qg = 0; qg < 2; ++qg) {
    const int qrow = sbase + w * 32 + qg * 16 + ln;
    qf[qg][0] = *(const bf16x8*)(Qp + (size_t)qrow * 64 + quad * 8);
    qf[qg][1] = *(const bf16x8*)(Qp + (size_t)qrow * 64 + 32 + quad * 8);
  }

  // ones B-frag (K=32): B[k][n]=1 iff n==0 -> lane ln==0 holds 8 ones
  const _Float16 one_h = (_Float16)((ln == 0) ? 1.0f : 0.0f);
  const f16x8 vf_one = (f16x8){one_h, one_h, one_h, one_h, one_h, one_h, one_h, one_h};

  const f32x4 zf = (f32x4){0.f, 0.f, 0.f, 0.f};  // hoisted zero C-operand

  f32x4 acc_o[2][4];
#pragma unroll
  for (int qg = 0; qg < 2; ++qg)
#pragma unroll
    for (int dg = 0; dg < 4; ++dg) acc_o[qg][dg] = zf;
  f32x4 acc_1[2] = {zf, zf};

  const int strow = t >> 2;
  const int stcol = (t & 3) * 16;       // global column base (ushorts)
  const int c0 = (t & 3) * 2;           // LDS chunk index (16B units), even
  const int gkw = (strow & 3) | (((strow >> 3) & 1) << 2);  // K write swizzle
  const int gvw = strow & 7;                                // V write swizzle

  // per-lane base pointers (linear; last-iter prefetch reads adjacent ws)
  const unsigned short* Kl = Kp + (size_t)strow * 64 + stcol;
  const unsigned short* Vl = Vp + (size_t)strow * 2048 + stcol;

  bf16x8 kr0 = *(const bf16x8*)(Kl);
  bf16x8 kr1 = *(const bf16x8*)(Kl + 8);
  bf16x8 vr0 = *(const bf16x8*)(Vl);
  bf16x8 vr1 = *(const bf16x8*)(Vl + 8);
  *(bf16x8*)&K_lds[0][strow][(c0 ^ gkw) << 3] = kr0;
  *(bf16x8*)&K_lds[0][strow][((c0 + 1) ^ gkw) << 3] = kr1;
  *(bf16x8*)&V_lds[0][strow][(c0 ^ gvw) << 3] = vr0;
  *(bf16x8*)&V_lds[0][strow][((c0 + 1) ^ gvw) << 3] = vr1;
  unsigned long long m0 = Mw[0], m1 = Mw[16];  // masks for qg=0/1, kt=0
  __syncthreads();

  const int kperm = ((ln >> 2) << 3) + (ln & 3);             // permuted K row base
  const int gkr = (ln & 3) | (((ln >> 2) & 1) << 2);         // = K swizzle of krow
  const int gvr = ln & 7;                                    // = V swizzle of vrow
  const int kc = (quad ^ gkr) << 3;                          // phys col of chunk `quad`

#pragma unroll 2
  for (int kt = 0; kt < 32; ++kt) {
    const int cur = kt & 1, nxt = cur ^ 1;

    // next-tile global prefetch (drained at LDS writes / next-iter use)
    kr0 = *(const bf16x8*)(Kl + (size_t)(kt + 1) * 4096);
    kr1 = *(const bf16x8*)(Kl + (size_t)(kt + 1) * 4096 + 8);
    vr0 = *(const bf16x8*)(Vl + (kt + 1) * 64);
    vr1 = *(const bf16x8*)(Vl + (kt + 1) * 64 + 8);
    const unsigned long long m0n = Mw[(size_t)(kt + 1) * 2048];
    const unsigned long long m1n = Mw[(size_t)(kt + 1) * 2048 + 16];

    // S^T with permuted key rows: frag f=h*2+e covers keys h*32+quad*8+e*4+r
    f32x4 sc[2][4];
    __builtin_amdgcn_s_setprio(1);
#pragma unroll
    for (int h = 0; h < 2; ++h)
#pragma unroll
      for (int e = 0; e < 2; ++e) {
        const int krow = h * 32 + kperm + e * 4;
        bf16x8 kf0 = *(const bf16x8*)&K_lds[cur][krow][kc];
        bf16x8 kf1 = *(const bf16x8*)&K_lds[cur][krow][kc ^ 32];  // chunk quad+4
#pragma unroll
        for (int qg = 0; qg < 2; ++qg) {
          f32x4 z = __builtin_amdgcn_mfma_f32_16x16x32_bf16(kf0, qf[qg][0], zf, 0, 0, 0);
          sc[qg][h * 2 + e] = __builtin_amdgcn_mfma_f32_16x16x32_bf16(kf1, qf[qg][1], z, 0, 0, 0);
        }
      }
    __builtin_amdgcn_s_setprio(0);

    // hoist V-frags (b128): B[k=quad*8+j][n=d] = V_lds[d][h*32+quad*8]
    f16x8 vfa[2][4];
#pragma unroll
    for (int h = 0; h < 2; ++h)
#pragma unroll
      for (int dg = 0; dg < 4; ++dg)
        vfa[h][dg] = *(const f16x8*)&V_lds[cur][dg * 16 + ln][((h * 4 + quad) ^ gvr) << 3];

    // mask (sign-mask AND) + exp2 -> P in K=32 A-slot order, packed cvt
    f16x8 pa[2][2];
#pragma unroll
    for (int qg = 0; qg < 2; ++qg) {
      const unsigned long long m64 = qg ? m1 : m0;
#pragma unroll
      for (int h = 0; h < 2; ++h) {
        const unsigned wrd = (h ? (unsigned)(m64 >> 32) : (unsigned)m64) >> (quad * 8);
        float p[8];
#pragma unroll
        for (int e = 0; e < 2; ++e)
#pragma unroll
          for (int r = 0; r < 4; ++r) {
            const int j = e * 4 + r;
            const int se = sbit(wrd, j);
            const float s = __int_as_float(__float_as_int(sc[qg][h * 2 + e][r]) & se);
            p[j] = EXP2F(s);
          }
        pa[qg][h] = pk8(p);
      }
    }

    // O += P @ V (K=32) ; lsum += P @ ones (col 0 of acc_1)
    __builtin_amdgcn_s_setprio(1);
#pragma unroll
    for (int h = 0; h < 2; ++h)
#pragma unroll
      for (int qg = 0; qg < 2; ++qg) {
#pragma unroll
        for (int dg = 0; dg < 4; ++dg)
          acc_o[qg][dg] = mfma_pv(pa[qg][h], vfa[h][dg], acc_o[qg][dg]);
        acc_1[qg] = mfma_pv(pa[qg][h], vf_one, acc_1[qg]);
      }
    __builtin_amdgcn_s_setprio(0);

    if (kt < 31) {
      *(bf16x8*)&K_lds[nxt][strow][(c0 ^ gkw) << 3] = kr0;
      *(bf16x8*)&K_lds[nxt][strow][((c0 + 1) ^ gkw) << 3] = kr1;
      *(bf16x8*)&V_lds[nxt][strow][(c0 ^ gvw) << 3] = vr0;
      *(bf16x8*)&V_lds[nxt][strow][((c0 + 1) ^ gvw) << 3] = vr1;
      __syncthreads();
    }
    m0 = m0n;
    m1 = m1n;
  }

  // epilogue: lsum for row q=quad*4+r lives in acc_1[qg][r] at lanes ln==0
  unsigned short* Op = Og + (size_t)bb * 2048 * 512 + (size_t)(bh & 7) * 64;
#pragma unroll
  for (int qg = 0; qg < 2; ++qg)
#pragma unroll
    for (int r = 0; r < 4; ++r) {
      const float inv = 1.0f / __shfl(acc_1[qg][r], quad * 16);
      const int sq = sbase + w * 32 + qg * 16 + quad * 4 + r;
#pragma unroll
      for (int dg = 0; dg < 4; ++dg)
        Op[(size_t)sq * 512 + dg * 16 + ln] = f2bf(acc_o[qg][dg][r] * inv);
    }
}

// ---------------------------------------------------------------------------
extern "C" void kernel_launch(void* const* d_in, const int* in_sizes, int n_in, void* d_out,
                              int out_size, void* d_ws, size_t ws_size, hipStream_t stream) {
  const float* x = (const float*)d_in[0];
  const float* adj = (const float*)d_in[1];
  const float* wqkv = (const float*)d_in[2];
  const float* bqkv = (const float*)d_in[3];
  const float* outw = (const float*)d_in[4];
  const float* outb = (const float*)d_in[5];
  float* out = (float*)d_out;

  char* ws = (char*)d_ws;
  unsigned short* x_bf = (unsigned short*)(ws);                      //  8.0 MB
  unsigned short* wqkv_bf = (unsigned short*)(ws + 8388608);         //  1.5 MB
  unsigned short* outw_bf = (unsigned short*)(ws + 9961472);         //  0.5 MB
  unsigned long long* abits = (unsigned long long*)(ws + 10485760);  //  2.0 MB
  unsigned short* Qb = (unsigned short*)(ws + 27262976);             //  8.0 MB (b,h,s,d) bf16
  unsigned short* Kb = (unsigned short*)(ws + 35651584);             //  8.0 MB (b,h,s,d) bf16
  unsigned short* Vb = (unsigned short*)(ws + 44040192);             //  8.0 MB (b,h,d,s) f16
  unsigned short* Ob = (unsigned short*)(ws + 52428800);             //  8.0 MB (b,s,e) bf16

  prep_k<<<7168, 256, 0, stream>>>(x, x_bf, wqkv, wqkv_bf, outw, outw_bf, adj, abits);

  gemm128_k<0><<<768, 256, 0, stream>>>(x_bf, wqkv_bf, bqkv, 512, 12, Qb, Kb, Vb, nullptr);

  attn_k<<<512, 256, 0, stream>>>(Qb, Kb, Vb, abits, Ob);

  gemm128_k<1><<<256, 256, 0, stream>>>(Ob, outw_bf, outb, 512, 4, nullptr, nullptr, nullptr, out);
}